// Round 1
// baseline (203.251 us; speedup 1.0000x reference)
//
#include <hip/hip_runtime.h>
#include <math.h>

// CustomQuaternionLoss — MI355X (gfx950)
// Memory-bound scalar-reduction kernel. See journal: ideal traffic ~55-65MB
// (batch_X last-row reads cost one 64B line per element), target ~10-12us.

#define DT_F 0.005f
#define EPS_F 1e-9f

__global__ __launch_bounds__(256) void quat_loss_main(
    const float* __restrict__ tq,     // (B,4)  true_quaternions (xyzw-conj'd later)
    const float* __restrict__ bias,   // (B,3)  predicted_biases
    const float* __restrict__ bX,     // (B,S,6) batch_X
    const float* __restrict__ qall,   // (N,4)  quaternions_all
    const float* __restrict__ xmean,  // (1,1,6)
    const float* __restrict__ xstd,   // (1,1,6)
    const int*   __restrict__ idx,    // (B,)
    float* __restrict__ partial,      // (gridDim.x,) per-block sums -> d_ws
    int B, int S)
{
    const int i = blockIdx.x * 256 + threadIdx.x;
    float local = 0.0f;

    // uniform broadcast loads (L1-cached, same address all lanes)
    const float m3 = xmean[3], m4 = xmean[4], m5 = xmean[5];
    const float s3 = xstd[3],  s4 = xstd[4],  s5 = xstd[5];

    if (i < B) {
        // ---- ang = batch_X[i, S-1, 3:6] * std + mean ----
        const size_t rowoff = ((size_t)i * S + (S - 1)) * 6;
        const float* xr = bX + rowoff + 3;
        const float ax = xr[0] * s3 + m3;
        const float ay = xr[1] * s4 + m4;
        const float az = xr[2] * s5 + m5;

        // ---- w_corr = ang - bias (DISTURBANCE == 0) ----
        const float* br = bias + (size_t)i * 3;
        const float wx = ax - br[0];
        const float wy = ay - br[1];
        const float wz = az - br[2];

        // ---- axis-angle increment quaternion (wxyz), then normalize ----
        const float n  = sqrtf(wx * wx + wy * wy + wz * wz);
        const float half = (n * DT_F) * 0.5f;
        const float ch = cosf(half);
        const float s  = sinf(half) / n;      // unguarded, same as reference
        float c0 = ch, c1 = s * wx, c2 = s * wy, c3 = s * wz;
        {
            const float inv = 1.0f / sqrtf(c0 * c0 + c1 * c1 + c2 * c2 + c3 * c3);
            c0 *= inv; c1 *= inv; c2 *= inv; c3 *= inv;
        }

        // ---- q0 = quaternions_all[max(idx - (S-1), 0)], normalized ----
        int ii = idx[i] - (S - 1);
        if (ii < 0) ii = 0;
        const float4 q0 = *reinterpret_cast<const float4*>(qall + (size_t)ii * 4);
        float a0 = q0.x, a1 = q0.y, a2 = q0.z, a3 = q0.w;
        {
            const float inv = 1.0f / sqrtf(a0 * a0 + a1 * a1 + a2 * a2 + a3 * a3);
            a0 *= inv; a1 *= inv; a2 *= inv; a3 *= inv;
        }

        // ---- q_comp = _quat_mul(q0n, corr)  (wxyz convention) ----
        const float p0 = a0 * c0 - a1 * c1 - a2 * c2 - a3 * c3;
        const float p1 = a0 * c1 + a1 * c0 + a2 * c3 - a3 * c2;
        const float p2 = a0 * c2 - a1 * c3 + a2 * c0 + a3 * c1;
        const float p3 = a0 * c3 + a1 * c2 - a2 * c1 + a3 * c0;

        // ---- tq_conj = (-t0, -t1, -t2, t3) ----
        const float4 t = *reinterpret_cast<const float4*>(tq + (size_t)i * 4);
        const float e0 = -t.x, e1 = -t.y, e2 = -t.z, e3 = t.w;

        // ---- q_diff = _quat_mul_xyzw(q_comp, tq_conj) ----
        // p -> (x1,y1,z1,w1) = (p0,p1,p2,p3); e -> (x2,y2,z2,w2)
        float d0 = p3 * e0 + p0 * e3 + p1 * e2 - p2 * e1;
        float d1 = p3 * e1 - p0 * e2 + p1 * e3 + p2 * e0;
        float d2 = p3 * e2 + p0 * e1 - p1 * e0 + p2 * e3;
        float d3 = p3 * e3 - p0 * e0 - p1 * e1 - p2 * e2;

        // ---- rotvec (xyzw) ----
        {
            const float inv = 1.0f / sqrtf(d0 * d0 + d1 * d1 + d2 * d2 + d3 * d3);
            d0 *= inv; d1 *= inv; d2 *= inv; d3 *= inv;
        }
        if (d3 < 0.0f) { d0 = -d0; d1 = -d1; d2 = -d2; d3 = -d3; }
        const float nv = sqrtf(d0 * d0 + d1 * d1 + d2 * d2);
        const float angle = 2.0f * atan2f(nv, d3);
        const float scale = (nv < EPS_F) ? 2.0f : angle / fmaxf(nv, EPS_F);
        const float r0 = d0 * scale, r1 = d1 * scale, r2 = d2 * scale;

        // ---- huber, summed over the 3 components ----
        const float h0 = (fabsf(r0) <= 1.0f) ? 0.5f * r0 * r0 : fabsf(r0) - 0.5f;
        const float h1 = (fabsf(r1) <= 1.0f) ? 0.5f * r1 * r1 : fabsf(r1) - 0.5f;
        const float h2 = (fabsf(r2) <= 1.0f) ? 0.5f * r2 * r2 : fabsf(r2) - 0.5f;
        local = h0 + h1 + h2;
    }

    // ---- block reduction: wave64 shfl, then LDS across the 4 waves ----
    #pragma unroll
    for (int o = 32; o > 0; o >>= 1) local += __shfl_down(local, o);
    __shared__ float red[4];
    if ((threadIdx.x & 63) == 0) red[threadIdx.x >> 6] = local;
    __syncthreads();
    if (threadIdx.x == 0)
        partial[blockIdx.x] = red[0] + red[1] + red[2] + red[3];
}

__global__ __launch_bounds__(256) void quat_loss_finish(
    const float* __restrict__ partial, int nb, float* __restrict__ out,
    double inv_count)
{
    double s = 0.0;
    for (int i = threadIdx.x; i < nb; i += 256) s += (double)partial[i];
    #pragma unroll
    for (int o = 32; o > 0; o >>= 1) s += __shfl_down(s, o);
    __shared__ double red[4];
    if ((threadIdx.x & 63) == 0) red[threadIdx.x >> 6] = s;
    __syncthreads();
    if (threadIdx.x == 0)
        out[0] = (float)((red[0] + red[1] + red[2] + red[3]) * inv_count);
}

extern "C" void kernel_launch(void* const* d_in, const int* in_sizes, int n_in,
                              void* d_out, int out_size, void* d_ws, size_t ws_size,
                              hipStream_t stream) {
    const float* tq    = (const float*)d_in[0];
    const float* bias  = (const float*)d_in[1];
    const float* bX    = (const float*)d_in[2];
    const float* qall  = (const float*)d_in[3];
    const float* xmean = (const float*)d_in[4];
    const float* xstd  = (const float*)d_in[5];
    const int*   idx   = (const int*)d_in[6];
    // d_in[7] = sequence_length (scalar); derive S from shapes instead.

    const int B = in_sizes[0] / 4;
    const int S = in_sizes[2] / (B * 6);
    const int nb = (B + 255) / 256;

    float* partial = (float*)d_ws;  // nb floats, fully rewritten every launch

    quat_loss_main<<<nb, 256, 0, stream>>>(tq, bias, bX, qall, xmean, xstd,
                                           idx, partial, B, S);
    const double inv_count = 1.0 / (3.0 * (double)B);
    quat_loss_finish<<<1, 256, 0, stream>>>(partial, nb, (float*)d_out, inv_count);
}

// Round 3
// 194.955 us; speedup vs baseline: 1.0426x; 1.0426x over previous
//
#include <hip/hip_runtime.h>
#include <math.h>

// CustomQuaternionLoss — MI355X (gfx950), round 3.
// R1: 203us total; harness reset (480MB poison fill 74us + input restore)
// dominates; our kernels own ~50-70us. R2 failed compile: nontemporal builtin
// needs clang ext_vector types, not HIP_vector_type. This round = R2 plan with
// ext_vector_type loads: 2 elems/thread, nontemporal streaming, double partials.

#define DT_F 0.005f
#define EPS_F 1e-9f

typedef float f4v __attribute__((ext_vector_type(4)));
typedef float f2v __attribute__((ext_vector_type(2)));
typedef int   i2v __attribute__((ext_vector_type(2)));

__device__ __forceinline__ float elem_huber(
    float bx0, float bx1, float bx2,        // batch_X[i, S-1, 3:6]
    float bi0, float bi1, float bi2,        // predicted_biases[i]
    f4v t,                                  // true_quaternions[i]
    const float* __restrict__ qall, int ii, // gather row (clamped)
    float s3, float s4, float s5, float m3, float m4, float m5)
{
    // ang = bX*std + mean ; w_corr = ang - bias  (DISTURBANCE == 0)
    const float wx = (bx0 * s3 + m3) - bi0;
    const float wy = (bx1 * s4 + m4) - bi1;
    const float wz = (bx2 * s5 + m5) - bi2;

    // axis-angle increment quaternion (wxyz), normalized
    const float n  = sqrtf(wx * wx + wy * wy + wz * wz);
    const float half = (n * DT_F) * 0.5f;
    const float ch = cosf(half);
    const float s  = sinf(half) / n;          // unguarded, same as reference
    float c0 = ch, c1 = s * wx, c2 = s * wy, c3 = s * wz;
    {
        const float inv = 1.0f / sqrtf(c0 * c0 + c1 * c1 + c2 * c2 + c3 * c3);
        c0 *= inv; c1 *= inv; c2 *= inv; c3 *= inv;
    }

    // q0 = quaternions_all[ii], normalized (cached load — want L2 residency)
    const f4v q0 = *reinterpret_cast<const f4v*>(qall + (size_t)ii * 4);
    float a0 = q0.x, a1 = q0.y, a2 = q0.z, a3 = q0.w;
    {
        const float inv = 1.0f / sqrtf(a0 * a0 + a1 * a1 + a2 * a2 + a3 * a3);
        a0 *= inv; a1 *= inv; a2 *= inv; a3 *= inv;
    }

    // q_comp = quat_mul_wxyz(q0n, corr)
    const float p0 = a0 * c0 - a1 * c1 - a2 * c2 - a3 * c3;
    const float p1 = a0 * c1 + a1 * c0 + a2 * c3 - a3 * c2;
    const float p2 = a0 * c2 - a1 * c3 + a2 * c0 + a3 * c1;
    const float p3 = a0 * c3 + a1 * c2 - a2 * c1 + a3 * c0;

    // tq_conj (xyzw): (-x,-y,-z,w)
    const float e0 = -t.x, e1 = -t.y, e2 = -t.z, e3 = t.w;

    // q_diff = quat_mul_xyzw(q_comp, tq_conj)
    float d0 = p3 * e0 + p0 * e3 + p1 * e2 - p2 * e1;
    float d1 = p3 * e1 - p0 * e2 + p1 * e3 + p2 * e0;
    float d2 = p3 * e2 + p0 * e1 - p1 * e0 + p2 * e3;
    float d3 = p3 * e3 - p0 * e0 - p1 * e1 - p2 * e2;

    // rotvec (xyzw)
    {
        const float inv = 1.0f / sqrtf(d0 * d0 + d1 * d1 + d2 * d2 + d3 * d3);
        d0 *= inv; d1 *= inv; d2 *= inv; d3 *= inv;
    }
    if (d3 < 0.0f) { d0 = -d0; d1 = -d1; d2 = -d2; d3 = -d3; }
    const float nv = sqrtf(d0 * d0 + d1 * d1 + d2 * d2);
    const float angle = 2.0f * atan2f(nv, d3);
    const float scale = (nv < EPS_F) ? 2.0f : angle / fmaxf(nv, EPS_F);
    const float r0 = d0 * scale, r1 = d1 * scale, r2 = d2 * scale;

    const float h0 = (fabsf(r0) <= 1.0f) ? 0.5f * r0 * r0 : fabsf(r0) - 0.5f;
    const float h1 = (fabsf(r1) <= 1.0f) ? 0.5f * r1 * r1 : fabsf(r1) - 0.5f;
    const float h2 = (fabsf(r2) <= 1.0f) ? 0.5f * r2 * r2 : fabsf(r2) - 0.5f;
    return h0 + h1 + h2;
}

__global__ __launch_bounds__(256) void quat_loss_main(
    const float* __restrict__ tq,     // (B,4)
    const float* __restrict__ bias,   // (B,3)
    const float* __restrict__ bX,     // (B,S,6)
    const float* __restrict__ qall,   // (N,4)
    const float* __restrict__ xmean,  // (1,1,6)
    const float* __restrict__ xstd,   // (1,1,6)
    const int*   __restrict__ idx,    // (B,)
    double* __restrict__ partial,     // (gridDim.x,)
    int B, int S)
{
    const int t  = blockIdx.x * 256 + threadIdx.x;   // pair id
    const int i0 = 2 * t;

    const float m3 = xmean[3], m4 = xmean[4], m5 = xmean[5];
    const float s3 = xstd[3],  s4 = xstd[4],  s5 = xstd[5];

    double local = 0.0;

    if (i0 + 1 < B) {
        // ---- indices ----
        const i2v id = *reinterpret_cast<const i2v*>(idx + i0);
        int ii0 = id.x - (S - 1); if (ii0 < 0) ii0 = 0;
        int ii1 = id.y - (S - 1); if (ii1 < 0) ii1 = 0;

        // ---- streamed inputs: nontemporal (single-use, keep L2 for qall) ----
        const f4v* tp = reinterpret_cast<const f4v*>(tq + (size_t)i0 * 4);
        const f4v tA = __builtin_nontemporal_load(tp);
        const f4v tB = __builtin_nontemporal_load(tp + 1);

        const f2v* bp = reinterpret_cast<const f2v*>(bias + (size_t)t * 6);
        const f2v b01 = __builtin_nontemporal_load(bp + 0);
        const f2v b23 = __builtin_nontemporal_load(bp + 1);
        const f2v b45 = __builtin_nontemporal_load(bp + 2);

        // batch_X row i: floats [i*6S + 6S-3 .. 6S-1]; for S=10: i*60+57 (odd)
        const size_t f0 = (size_t)i0 * 6 * S + 6 * S - 3;
        const size_t f1 = f0 + 6 * S;
        const float xA0 = __builtin_nontemporal_load(bX + f0);
        const f2v  xA12 = __builtin_nontemporal_load(
                              reinterpret_cast<const f2v*>(bX + f0 + 1));
        const float xB0 = __builtin_nontemporal_load(bX + f1);
        const f2v  xB12 = __builtin_nontemporal_load(
                              reinterpret_cast<const f2v*>(bX + f1 + 1));

        const float hA = elem_huber(xA0, xA12.x, xA12.y, b01.x, b01.y, b23.x,
                                    tA, qall, ii0, s3, s4, s5, m3, m4, m5);
        const float hB = elem_huber(xB0, xB12.x, xB12.y, b23.y, b45.x, b45.y,
                                    tB, qall, ii1, s3, s4, s5, m3, m4, m5);
        local = (double)hA + (double)hB;
    } else if (i0 < B) {
        // tail (not hit for B=524288, kept for generality)
        const f4v tA = *reinterpret_cast<const f4v*>(tq + (size_t)i0 * 4);
        int ii0 = idx[i0] - (S - 1); if (ii0 < 0) ii0 = 0;
        const float* br = bias + (size_t)i0 * 3;
        const size_t f0 = (size_t)i0 * 6 * S + 6 * S - 3;
        local = (double)elem_huber(bX[f0], bX[f0 + 1], bX[f0 + 2],
                                   br[0], br[1], br[2],
                                   tA, qall, ii0, s3, s4, s5, m3, m4, m5);
    }

    // ---- block reduction in double: wave64 shfl, then LDS across 4 waves ----
    #pragma unroll
    for (int o = 32; o > 0; o >>= 1) local += __shfl_down(local, o);
    __shared__ double red[4];
    if ((threadIdx.x & 63) == 0) red[threadIdx.x >> 6] = local;
    __syncthreads();
    if (threadIdx.x == 0)
        partial[blockIdx.x] = red[0] + red[1] + red[2] + red[3];
}

__global__ __launch_bounds__(256) void quat_loss_finish(
    const double* __restrict__ partial, int nb, float* __restrict__ out,
    double inv_count)
{
    double s = 0.0;
    for (int i = threadIdx.x; i < nb; i += 256) s += partial[i];
    #pragma unroll
    for (int o = 32; o > 0; o >>= 1) s += __shfl_down(s, o);
    __shared__ double red[4];
    if ((threadIdx.x & 63) == 0) red[threadIdx.x >> 6] = s;
    __syncthreads();
    if (threadIdx.x == 0)
        out[0] = (float)((red[0] + red[1] + red[2] + red[3]) * inv_count);
}

extern "C" void kernel_launch(void* const* d_in, const int* in_sizes, int n_in,
                              void* d_out, int out_size, void* d_ws, size_t ws_size,
                              hipStream_t stream) {
    const float* tq    = (const float*)d_in[0];
    const float* bias  = (const float*)d_in[1];
    const float* bX    = (const float*)d_in[2];
    const float* qall  = (const float*)d_in[3];
    const float* xmean = (const float*)d_in[4];
    const float* xstd  = (const float*)d_in[5];
    const int*   idx   = (const int*)d_in[6];

    const int B = in_sizes[0] / 4;
    const int S = in_sizes[2] / (B * 6);
    const int nb = (B + 511) / 512;          // 2 elements per thread

    double* partial = (double*)d_ws;         // nb doubles, rewritten each launch

    quat_loss_main<<<nb, 256, 0, stream>>>(tq, bias, bX, qall, xmean, xstd,
                                           idx, partial, B, S);
    const double inv_count = 1.0 / (3.0 * (double)B);
    quat_loss_finish<<<1, 256, 0, stream>>>(partial, nb, (float*)d_out, inv_count);
}

// Round 7
// 194.504 us; speedup vs baseline: 1.0450x; 1.0023x over previous
//
#include <hip/hip_runtime.h>
#include <math.h>

// CustomQuaternionLoss — MI355X (gfx950), round 7 (= round 4 kernel; R4/R5/R6
// all hit GPUAcquisitionTimeout and never ran — identical resubmission).
// R3: 195us total, absmax 0.0. Top-5 = harness 503MB poison fills only (73us,
// 86% HBM) => main kernel < 72us, likely 12-50us; fixed reset ~150-180us.
// This round: VMEM 14->10 per pair (aligned float4 bX covering floats 56..59
// of each 60-float row; nontemporal idx), gather chain issued first.
// If delta is within noise, remaining time is harness reset + ~10us HBM floor.

#define DT_F 0.005f
#define EPS_F 1e-9f

typedef float f4v __attribute__((ext_vector_type(4)));
typedef float f2v __attribute__((ext_vector_type(2)));
typedef int   i2v __attribute__((ext_vector_type(2)));

__device__ __forceinline__ float elem_huber(
    float bx0, float bx1, float bx2,        // batch_X[i, S-1, 3:6]
    float bi0, float bi1, float bi2,        // predicted_biases[i]
    f4v t,                                  // true_quaternions[i]
    f4v q0,                                 // quaternions_all[clamped idx]
    float s3, float s4, float s5, float m3, float m4, float m5)
{
    // ang = bX*std + mean ; w_corr = ang - bias  (DISTURBANCE == 0)
    const float wx = (bx0 * s3 + m3) - bi0;
    const float wy = (bx1 * s4 + m4) - bi1;
    const float wz = (bx2 * s5 + m5) - bi2;

    // axis-angle increment quaternion (wxyz), normalized
    const float n  = sqrtf(wx * wx + wy * wy + wz * wz);
    const float half = (n * DT_F) * 0.5f;
    const float ch = cosf(half);
    const float s  = sinf(half) / n;          // unguarded, same as reference
    float c0 = ch, c1 = s * wx, c2 = s * wy, c3 = s * wz;
    {
        const float inv = 1.0f / sqrtf(c0 * c0 + c1 * c1 + c2 * c2 + c3 * c3);
        c0 *= inv; c1 *= inv; c2 *= inv; c3 *= inv;
    }

    // q0 normalized
    float a0 = q0.x, a1 = q0.y, a2 = q0.z, a3 = q0.w;
    {
        const float inv = 1.0f / sqrtf(a0 * a0 + a1 * a1 + a2 * a2 + a3 * a3);
        a0 *= inv; a1 *= inv; a2 *= inv; a3 *= inv;
    }

    // q_comp = quat_mul_wxyz(q0n, corr)
    const float p0 = a0 * c0 - a1 * c1 - a2 * c2 - a3 * c3;
    const float p1 = a0 * c1 + a1 * c0 + a2 * c3 - a3 * c2;
    const float p2 = a0 * c2 - a1 * c3 + a2 * c0 + a3 * c1;
    const float p3 = a0 * c3 + a1 * c2 - a2 * c1 + a3 * c0;

    // tq_conj (xyzw): (-x,-y,-z,w)
    const float e0 = -t.x, e1 = -t.y, e2 = -t.z, e3 = t.w;

    // q_diff = quat_mul_xyzw(q_comp, tq_conj)
    float d0 = p3 * e0 + p0 * e3 + p1 * e2 - p2 * e1;
    float d1 = p3 * e1 - p0 * e2 + p1 * e3 + p2 * e0;
    float d2 = p3 * e2 + p0 * e1 - p1 * e0 + p2 * e3;
    float d3 = p3 * e3 - p0 * e0 - p1 * e1 - p2 * e2;

    // rotvec (xyzw)
    {
        const float inv = 1.0f / sqrtf(d0 * d0 + d1 * d1 + d2 * d2 + d3 * d3);
        d0 *= inv; d1 *= inv; d2 *= inv; d3 *= inv;
    }
    if (d3 < 0.0f) { d0 = -d0; d1 = -d1; d2 = -d2; d3 = -d3; }
    const float nv = sqrtf(d0 * d0 + d1 * d1 + d2 * d2);
    const float angle = 2.0f * atan2f(nv, d3);
    const float scale = (nv < EPS_F) ? 2.0f : angle / fmaxf(nv, EPS_F);
    const float r0 = d0 * scale, r1 = d1 * scale, r2 = d2 * scale;

    const float h0 = (fabsf(r0) <= 1.0f) ? 0.5f * r0 * r0 : fabsf(r0) - 0.5f;
    const float h1 = (fabsf(r1) <= 1.0f) ? 0.5f * r1 * r1 : fabsf(r1) - 0.5f;
    const float h2 = (fabsf(r2) <= 1.0f) ? 0.5f * r2 * r2 : fabsf(r2) - 0.5f;
    return h0 + h1 + h2;
}

__global__ __launch_bounds__(256) void quat_loss_main(
    const float* __restrict__ tq,     // (B,4)
    const float* __restrict__ bias,   // (B,3)
    const float* __restrict__ bX,     // (B,S,6)
    const float* __restrict__ qall,   // (N,4)
    const float* __restrict__ xmean,  // (1,1,6)
    const float* __restrict__ xstd,   // (1,1,6)
    const int*   __restrict__ idx,    // (B,)
    double* __restrict__ partial,     // (gridDim.x,)
    int B, int S)
{
    const int t  = blockIdx.x * 256 + threadIdx.x;   // pair id
    const int i0 = 2 * t;

    double local = 0.0;

    if (i0 + 1 < B) {
        // ---- gather chain first: idx -> clamp -> qall rows ----
        const i2v id = __builtin_nontemporal_load(
                           reinterpret_cast<const i2v*>(idx + i0));
        int ii0 = id.x - (S - 1); if (ii0 < 0) ii0 = 0;
        int ii1 = id.y - (S - 1); if (ii1 < 0) ii1 = 0;
        const f4v q0A = *reinterpret_cast<const f4v*>(qall + (size_t)ii0 * 4);
        const f4v q0B = *reinterpret_cast<const f4v*>(qall + (size_t)ii1 * 4);

        // ---- streamed single-use inputs: nontemporal ----
        const f4v* tp = reinterpret_cast<const f4v*>(tq + (size_t)i0 * 4);
        const f4v tA = __builtin_nontemporal_load(tp);
        const f4v tB = __builtin_nontemporal_load(tp + 1);

        const f2v* bp = reinterpret_cast<const f2v*>(bias + (size_t)t * 6);
        const f2v b01 = __builtin_nontemporal_load(bp + 0);
        const f2v b23 = __builtin_nontemporal_load(bp + 1);
        const f2v b45 = __builtin_nontemporal_load(bp + 2);

        // batch_X row i (60 floats): want floats 57..59; float4 at 56 is
        // 16B-aligned (i*240+224 ≡ 0 mod 16). One dwordx4 per element.
        const int SS = 6 * S;                 // 60
        const f4v xA = __builtin_nontemporal_load(
            reinterpret_cast<const f4v*>(bX + (size_t)i0 * SS + (SS - 4)));
        const f4v xB = __builtin_nontemporal_load(
            reinterpret_cast<const f4v*>(bX + (size_t)(i0 + 1) * SS + (SS - 4)));

        const float hA = elem_huber(xA.y, xA.z, xA.w, b01.x, b01.y, b23.x,
                                    tA, q0A, xstd[3], xstd[4], xstd[5],
                                    xmean[3], xmean[4], xmean[5]);
        const float hB = elem_huber(xB.y, xB.z, xB.w, b23.y, b45.x, b45.y,
                                    tB, q0B, xstd[3], xstd[4], xstd[5],
                                    xmean[3], xmean[4], xmean[5]);
        local = (double)hA + (double)hB;
    } else if (i0 < B) {
        // tail (not hit for B=524288, kept for generality; scalar loads)
        const f4v tA = *reinterpret_cast<const f4v*>(tq + (size_t)i0 * 4);
        int ii0 = idx[i0] - (S - 1); if (ii0 < 0) ii0 = 0;
        const f4v q0A = *reinterpret_cast<const f4v*>(qall + (size_t)ii0 * 4);
        const float* br = bias + (size_t)i0 * 3;
        const size_t f0 = (size_t)i0 * 6 * S + 6 * S - 3;
        local = (double)elem_huber(bX[f0], bX[f0 + 1], bX[f0 + 2],
                                   br[0], br[1], br[2], tA, q0A,
                                   xstd[3], xstd[4], xstd[5],
                                   xmean[3], xmean[4], xmean[5]);
    }

    // ---- block reduction in double: wave64 shfl, then LDS across 4 waves ----
    #pragma unroll
    for (int o = 32; o > 0; o >>= 1) local += __shfl_down(local, o);
    __shared__ double red[4];
    if ((threadIdx.x & 63) == 0) red[threadIdx.x >> 6] = local;
    __syncthreads();
    if (threadIdx.x == 0)
        partial[blockIdx.x] = red[0] + red[1] + red[2] + red[3];
}

__global__ __launch_bounds__(256) void quat_loss_finish(
    const double* __restrict__ partial, int nb, float* __restrict__ out,
    double inv_count)
{
    double s = 0.0;
    for (int i = threadIdx.x; i < nb; i += 256) s += partial[i];
    #pragma unroll
    for (int o = 32; o > 0; o >>= 1) s += __shfl_down(s, o);
    __shared__ double red[4];
    if ((threadIdx.x & 63) == 0) red[threadIdx.x >> 6] = s;
    __syncthreads();
    if (threadIdx.x == 0)
        out[0] = (float)((red[0] + red[1] + red[2] + red[3]) * inv_count);
}

extern "C" void kernel_launch(void* const* d_in, const int* in_sizes, int n_in,
                              void* d_out, int out_size, void* d_ws, size_t ws_size,
                              hipStream_t stream) {
    const float* tq    = (const float*)d_in[0];
    const float* bias  = (const float*)d_in[1];
    const float* bX    = (const float*)d_in[2];
    const float* qall  = (const float*)d_in[3];
    const float* xmean = (const float*)d_in[4];
    const float* xstd  = (const float*)d_in[5];
    const int*   idx   = (const int*)d_in[6];

    const int B = in_sizes[0] / 4;
    const int S = in_sizes[2] / (B * 6);
    const int nb = (B + 511) / 512;          // 2 elements per thread

    double* partial = (double*)d_ws;         // nb doubles, rewritten each launch

    quat_loss_main<<<nb, 256, 0, stream>>>(tq, bias, bX, qall, xmean, xstd,
                                           idx, partial, B, S);
    const double inv_count = 1.0 / (3.0 * (double)B);
    quat_loss_finish<<<1, 256, 0, stream>>>(partial, nb, (float*)d_out, inv_count);
}